// Round 1
// baseline (422.947 us; speedup 1.0000x reference)
//
#include <hip/hip_runtime.h>
#include <math.h>

#define K1 50176
#define N1 512
#define MM 512
#define BM 128
#define BN 64
#define BK 32

// ---------------- GEMM1: h1_partial[s] = A[:, ks:ke] @ W1[ks:ke, :] ----------------
// A = pred_map flat [512][50176], W1 [50176][512]. Split-K deterministic partials.
__global__ __launch_bounds__(256) void gemm1_splitk(
    const float* __restrict__ A,
    const float* __restrict__ B,
    float* __restrict__ part,
    int KC)
{
    __shared__ float As[BK][BM + 4];   // A stored transposed: As[k][m]
    __shared__ float Bs[BK][BN + 4];

    const int tid = threadIdx.x;
    const int bm = blockIdx.x, bn = blockIdx.y, s = blockIdx.z;
    const int k0 = s * KC;

    const float* Ab = A + (size_t)(bm * BM) * K1 + k0;
    const float* Bb = B + (size_t)k0 * N1 + bn * BN;

    int aRow[4], aC4[4], bRow[2], bC4[2];
#pragma unroll
    for (int r = 0; r < 4; ++r) { int slot = r * 256 + tid; aRow[r] = slot >> 3; aC4[r] = slot & 7; }
#pragma unroll
    for (int r = 0; r < 2; ++r) { int slot = r * 256 + tid; bRow[r] = slot >> 4; bC4[r] = slot & 15; }

    float4 aReg[4], bReg[2];

    auto load_tiles = [&](int kt) {
#pragma unroll
        for (int r = 0; r < 4; ++r)
            aReg[r] = *(const float4*)(Ab + (size_t)aRow[r] * K1 + kt + aC4[r] * 4);
#pragma unroll
        for (int r = 0; r < 2; ++r)
            bReg[r] = *(const float4*)(Bb + (size_t)(kt + bRow[r]) * N1 + bC4[r] * 4);
    };
    auto store_tiles = [&]() {
#pragma unroll
        for (int r = 0; r < 4; ++r) {
            As[aC4[r] * 4 + 0][aRow[r]] = aReg[r].x;
            As[aC4[r] * 4 + 1][aRow[r]] = aReg[r].y;
            As[aC4[r] * 4 + 2][aRow[r]] = aReg[r].z;
            As[aC4[r] * 4 + 3][aRow[r]] = aReg[r].w;
        }
#pragma unroll
        for (int r = 0; r < 2; ++r)
            *(float4*)&Bs[bRow[r]][bC4[r] * 4] = bReg[r];
    };

    float acc[8][4];
#pragma unroll
    for (int i = 0; i < 8; ++i)
#pragma unroll
        for (int j = 0; j < 4; ++j) acc[i][j] = 0.f;

    const int mo = (tid >> 4) * 8;   // 16 m-groups of 8
    const int no = (tid & 15) * 4;   // 16 n-groups of 4

    const int nIter = KC / BK;
    load_tiles(0);
    store_tiles();
    __syncthreads();

    for (int t = 0; t < nIter; ++t) {
        if (t + 1 < nIter) load_tiles((t + 1) * BK);
#pragma unroll 8
        for (int k = 0; k < BK; ++k) {
            float a0[8], b0[4];
            *(float4*)&a0[0] = *(const float4*)&As[k][mo];
            *(float4*)&a0[4] = *(const float4*)&As[k][mo + 4];
            *(float4*)&b0[0] = *(const float4*)&Bs[k][no];
#pragma unroll
            for (int i = 0; i < 8; ++i)
#pragma unroll
                for (int j = 0; j < 4; ++j)
                    acc[i][j] = fmaf(a0[i], b0[j], acc[i][j]);
        }
        __syncthreads();
        if (t + 1 < nIter) store_tiles();
        __syncthreads();
    }

    float* Cp = part + (size_t)s * (MM * N1) + (size_t)(bm * BM + mo) * N1 + bn * BN + no;
#pragma unroll
    for (int i = 0; i < 8; ++i) {
        float4 v = make_float4(acc[i][0], acc[i][1], acc[i][2], acc[i][3]);
        *(float4*)(Cp + (size_t)i * N1) = v;
    }
}

// ---------------- reduce partials + bias + relu -> h1 ----------------
__global__ __launch_bounds__(256) void reduce_bias_relu(
    const float* __restrict__ part, const float* __restrict__ b1,
    float* __restrict__ h1, int S)
{
    int idx = blockIdx.x * 256 + threadIdx.x;   // 0..262143
    float sum = 0.f;
    for (int s = 0; s < S; ++s) sum += part[(size_t)s * 262144 + idx];
    sum += b1[idx & 511];
    h1[idx] = fmaxf(sum, 0.f);
}

// ---------------- layer 2: h2 = relu(h1 @ W2 + b2) ----------------
__global__ __launch_bounds__(256) void gemm2_k(
    const float* __restrict__ h1, const float* __restrict__ W2,
    const float* __restrict__ b2, float* __restrict__ h2)
{
    int g = blockIdx.x * 256 + threadIdx.x;     // 0..131071
    int m = g >> 8, n = g & 255;
    const float* a = h1 + (size_t)m * 512;
    float sum = 0.f;
#pragma unroll 8
    for (int k = 0; k < 512; ++k) sum = fmaf(a[k], W2[(size_t)k * 256 + n], sum);
    sum += b2[n];
    h2[g] = fmaxf(sum, 0.f);
}

// ---------------- layer 3: pred = sigmoid(h2 @ W3 + b3) ----------------
__global__ __launch_bounds__(256) void gemm3_sig(
    const float* __restrict__ h2, const float* __restrict__ W3,
    const float* __restrict__ b3, float* __restrict__ pred)
{
    int g = blockIdx.x * 256 + threadIdx.x;     // 0..8191
    int m = g >> 4, j = g & 15;
    const float* a = h2 + (size_t)m * 256;
    float sum = 0.f;
#pragma unroll 8
    for (int k = 0; k < 256; ++k) sum = fmaf(a[k], W3[(size_t)k * 16 + j], sum);
    sum += b3[j];
    pred[g] = 1.f / (1.f + expf(-sum));
}

// ---------------- patch gathers ----------------
__device__ __forceinline__ int clip_coord(float v) {
    int c = (int)(v * 224.0f);      // matches astype(int32) truncation
    if (c >= 219) c = 200;
    if (c <= 5)   c = 8;
    return c;
}

__global__ void patches_k(
    const float* __restrict__ pm, const float* __restrict__ gt,
    const float* __restrict__ pred, float* __restrict__ out)
{
    const int b = blockIdx.x;
    const int t = threadIdx.x;          // 0..287
    const int lm = t / 36, cell = t % 36;
    const int dx = cell / 6 - 3, dy = cell % 6 - 3;
    const float* pmb = pm + (size_t)b * 50176;

    // GT patch
    {
        int cx = clip_coord(gt[b * 16 + lm * 2 + 0]);
        int cy = clip_coord(gt[b * 16 + lm * 2 + 1]);
        out[8192 + b * 288 + t] = pmb[(cx + dx) * 224 + (cy + dy)];
    }
    // Pred patch
    {
        int cx = clip_coord(pred[b * 16 + lm * 2 + 0]);
        int cy = clip_coord(pred[b * 16 + lm * 2 + 1]);
        out[8192 + 147456 + b * 288 + t] = pmb[(cx + dx) * 224 + (cy + dy)];
    }
}

extern "C" void kernel_launch(void* const* d_in, const int* in_sizes, int n_in,
                              void* d_out, int out_size, void* d_ws, size_t ws_size,
                              hipStream_t stream)
{
    const float* pred_map = (const float*)d_in[0];
    const float* gt       = (const float*)d_in[1];
    const float* W1       = (const float*)d_in[2];
    const float* b1       = (const float*)d_in[3];
    const float* W2       = (const float*)d_in[4];
    const float* b2       = (const float*)d_in[5];
    const float* W3       = (const float*)d_in[6];
    const float* b3       = (const float*)d_in[7];
    float* out = (float*)d_out;

    float* h1   = (float*)d_ws;          // 262144 floats
    float* h2   = h1 + 262144;           // 131072 floats
    float* part = h2 + 131072;           // S * 262144 floats

    // deterministic split-K factor chosen from available workspace
    int S = 16;
    while (S > 1 && (size_t)(393216 + (size_t)S * 262144) * sizeof(float) > ws_size) S >>= 1;
    int KC = K1 / S;   // 50176 divisible by 1,2,4,8,16

    hipLaunchKernelGGL(gemm1_splitk, dim3(MM / BM, N1 / BN, S), dim3(256), 0, stream,
                       pred_map, W1, part, KC);
    hipLaunchKernelGGL(reduce_bias_relu, dim3(262144 / 256), dim3(256), 0, stream,
                       part, b1, h1, S);
    hipLaunchKernelGGL(gemm2_k, dim3(131072 / 256), dim3(256), 0, stream, h1, W2, b2, h2);
    hipLaunchKernelGGL(gemm3_sig, dim3(8192 / 256), dim3(256), 0, stream, h2, W3, b3, out);
    hipLaunchKernelGGL(patches_k, dim3(512), dim3(288), 0, stream, pred_map, gt, out, out);
}

// Round 2
// 264.483 us; speedup vs baseline: 1.5991x; 1.5991x over previous
//
#include <hip/hip_runtime.h>
#include <math.h>

typedef __attribute__((ext_vector_type(8))) short   s16x8;   // 8 bf16 in 4 VGPRs
typedef __attribute__((ext_vector_type(8))) unsigned short u16x8;
typedef __attribute__((ext_vector_type(4))) float   f32x4;

#define KDIM 50176
#define NDIM 512
#define MDIM 512
#define BMT  256
#define BNT  256
#define BKT  32
#define NSTEPS 1568   // KDIM / BKT

// round-to-nearest-even fp32 -> bf16, also returns the rounded value as fp32
__device__ __forceinline__ unsigned short bf16rn(float v, float& fv) {
    unsigned u = __float_as_uint(v);
    unsigned r = (u + 0x7FFFu + ((u >> 16) & 1u)) >> 16;
    fv = __uint_as_float(r << 16);
    return (unsigned short)r;
}

// exact 3-term split: v = h + m + l + O(2^-24 v)
__device__ __forceinline__ void split3(float v, unsigned short& h, unsigned short& m, unsigned short& l) {
    float fh, fm, fl;
    h = bf16rn(v, fh);
    float r1 = v - fh;        // exact (Dekker)
    m = bf16rn(r1, fm);
    float r2 = r1 - fm;       // exact
    l = bf16rn(r2, fl);
}

// ------------- GEMM1 via bf16 MFMA, 3-way split (6 products), split-K -------------
__global__ __launch_bounds__(512, 2) void gemm1_mfma(
    const float* __restrict__ A,      // [512][50176]
    const float* __restrict__ W,      // [50176][512]
    float* __restrict__ part,         // [S][512][512]
    int steps_per, int rem)
{
    __shared__ unsigned short Apl[3][256][32];   // [plane][m][k] bf16, 48 KB
    __shared__ unsigned short Bpl[3][256][32];   // [plane][n][k] bf16, 48 KB
    __shared__ float          Wtmp[32][256];     // fp32 W tile [k][n], 32 KB

    const int t  = threadIdx.x;
    const int bm = blockIdx.x, bn = blockIdx.y, z = blockIdx.z;
    const int base = z * steps_per + (z < rem ? z : rem);
    const int cnt  = steps_per + (z < rem ? 1 : 0);

    // A staging: 8 lanes per 128B row, rows ar+64j
    const int ar = t >> 3, ac = t & 7;
    // W staging: k-rows wr+8j, float4 col wc
    const int wr = t >> 6, wc = t & 63;
    // W transpose-convert pass
    const int nn = t & 255, kh = (t >> 8) << 4;

    const int lane = t & 63, wave = t >> 6;
    const int wm = wave >> 1, wn = wave & 1;       // 4 x 2 wave grid -> 64x128 tiles
    const int l15 = lane & 15, lh = lane >> 4;

    f32x4 acc[4][8];
#pragma unroll
    for (int i = 0; i < 4; ++i)
#pragma unroll
        for (int j = 0; j < 8; ++j) acc[i][j] = (f32x4)0.f;

    float4 aReg[4], wReg[4];
    auto gload = [&](int step) {
        const int kpos = step * BKT;
        const float* Ab = A + (size_t)(bm * BMT) * KDIM + kpos;
#pragma unroll
        for (int j = 0; j < 4; ++j)
            aReg[j] = *(const float4*)(Ab + (size_t)(ar + 64 * j) * KDIM + ac * 4);
        const float* Wb = W + (size_t)kpos * NDIM + bn * BNT;
#pragma unroll
        for (int j = 0; j < 4; ++j)
            wReg[j] = *(const float4*)(Wb + (size_t)(wr + 8 * j) * NDIM + wc * 4);
    };

    gload(base);

    for (int s = 0; s < cnt; ++s) {
        // ---- stage regs -> LDS (A converted to 3 planes; W as fp32 temp) ----
#pragma unroll
        for (int j = 0; j < 4; ++j) {
            const int m = ar + 64 * j;
            float vv[4] = {aReg[j].x, aReg[j].y, aReg[j].z, aReg[j].w};
            unsigned short hh[4], mv[4], lv[4];
#pragma unroll
            for (int e = 0; e < 4; ++e) split3(vv[e], hh[e], mv[e], lv[e]);
            *(ushort4*)&Apl[0][m][ac * 4] = make_ushort4(hh[0], hh[1], hh[2], hh[3]);
            *(ushort4*)&Apl[1][m][ac * 4] = make_ushort4(mv[0], mv[1], mv[2], mv[3]);
            *(ushort4*)&Apl[2][m][ac * 4] = make_ushort4(lv[0], lv[1], lv[2], lv[3]);
            *(float4*)&Wtmp[wr + 8 * j][wc * 4] = wReg[j];
        }
        __syncthreads();

        // ---- transpose-convert W: Wtmp[k][n] -> Bpl[p][n][k] ----
        {
            u16x8 th0, th1, tm0, tm1, tl0, tl1;
#pragma unroll
            for (int jj = 0; jj < 8; ++jj) {
                unsigned short h_, m_, l_;
                split3(Wtmp[kh + jj][nn], h_, m_, l_);
                th0[jj] = h_; tm0[jj] = m_; tl0[jj] = l_;
            }
#pragma unroll
            for (int jj = 0; jj < 8; ++jj) {
                unsigned short h_, m_, l_;
                split3(Wtmp[kh + 8 + jj][nn], h_, m_, l_);
                th1[jj] = h_; tm1[jj] = m_; tl1[jj] = l_;
            }
            *(u16x8*)&Bpl[0][nn][kh] = th0; *(u16x8*)&Bpl[0][nn][kh + 8] = th1;
            *(u16x8*)&Bpl[1][nn][kh] = tm0; *(u16x8*)&Bpl[1][nn][kh + 8] = tm1;
            *(u16x8*)&Bpl[2][nn][kh] = tl0; *(u16x8*)&Bpl[2][nn][kh + 8] = tl1;
        }

        // prefetch next tile (overlaps with compute below)
        if (s + 1 < cnt) gload(base + s + 1);
        __syncthreads();

        // ---- compute: 6 plane-products, 4x8 fragments, K=32 per MFMA ----
#pragma unroll
        for (int pa = 0; pa < 3; ++pa) {
            s16x8 af[4];
#pragma unroll
            for (int mf = 0; mf < 4; ++mf)
                af[mf] = *(const s16x8*)&Apl[pa][wm * 64 + mf * 16 + l15][lh * 8];
            const int npb = (pa == 0) ? 3 : (pa == 1 ? 2 : 1);
#pragma unroll
            for (int pb = 0; pb < 3; ++pb) {
                if (pb >= npb) continue;
#pragma unroll
                for (int nf = 0; nf < 8; ++nf) {
                    s16x8 bfrag = *(const s16x8*)&Bpl[pb][wn * 128 + nf * 16 + l15][lh * 8];
#pragma unroll
                    for (int mf = 0; mf < 4; ++mf)
                        acc[mf][nf] = __builtin_amdgcn_mfma_f32_16x16x32_bf16(
                            af[mf], bfrag, acc[mf][nf], 0, 0, 0);
                }
            }
        }
        __syncthreads();
    }

    // ---- store partials: C/D layout col=lane&15, row=(lane>>4)*4+r ----
    float* Cp = part + (size_t)z * (MDIM * NDIM);
    const int row0 = bm * BMT + wm * 64;
    const int col0 = bn * BNT + wn * 128;
#pragma unroll
    for (int mf = 0; mf < 4; ++mf)
#pragma unroll
        for (int nf = 0; nf < 8; ++nf) {
            const int r0 = row0 + mf * 16 + lh * 4;
            const int c  = col0 + nf * 16 + l15;
#pragma unroll
            for (int r = 0; r < 4; ++r)
                Cp[(size_t)(r0 + r) * NDIM + c] = acc[mf][nf][r];
        }
}

// ---------------- reduce partials + bias + relu -> h1 ----------------
__global__ __launch_bounds__(256) void reduce_bias_relu(
    const float* __restrict__ part, const float* __restrict__ b1,
    float* __restrict__ h1, int S)
{
    int idx = blockIdx.x * 256 + threadIdx.x;   // 0..262143
    float sum = 0.f;
    for (int s = 0; s < S; ++s) sum += part[(size_t)s * 262144 + idx];
    sum += b1[idx & 511];
    h1[idx] = fmaxf(sum, 0.f);
}

// ---------------- layer 2: h2 = relu(h1 @ W2 + b2) ----------------
__global__ __launch_bounds__(256) void gemm2_k(
    const float* __restrict__ h1, const float* __restrict__ W2,
    const float* __restrict__ b2, float* __restrict__ h2)
{
    int g = blockIdx.x * 256 + threadIdx.x;     // 0..131071
    int m = g >> 8, n = g & 255;
    const float* a = h1 + (size_t)m * 512;
    float sum = 0.f;
#pragma unroll 8
    for (int k = 0; k < 512; ++k) sum = fmaf(a[k], W2[(size_t)k * 256 + n], sum);
    sum += b2[n];
    h2[g] = fmaxf(sum, 0.f);
}

// ---------------- layer 3: pred = sigmoid(h2 @ W3 + b3) ----------------
__global__ __launch_bounds__(256) void gemm3_sig(
    const float* __restrict__ h2, const float* __restrict__ W3,
    const float* __restrict__ b3, float* __restrict__ pred)
{
    int g = blockIdx.x * 256 + threadIdx.x;     // 0..8191
    int m = g >> 4, j = g & 15;
    const float* a = h2 + (size_t)m * 256;
    float sum = 0.f;
#pragma unroll 8
    for (int k = 0; k < 256; ++k) sum = fmaf(a[k], W3[(size_t)k * 16 + j], sum);
    sum += b3[j];
    pred[g] = 1.f / (1.f + expf(-sum));
}

// ---------------- patch gathers ----------------
__device__ __forceinline__ int clip_coord(float v) {
    int c = (int)(v * 224.0f);
    if (c >= 219) c = 200;
    if (c <= 5)   c = 8;
    return c;
}

__global__ void patches_k(
    const float* __restrict__ pm, const float* __restrict__ gt,
    const float* __restrict__ pred, float* __restrict__ out)
{
    const int b = blockIdx.x;
    const int t = threadIdx.x;          // 0..287
    const int lm = t / 36, cell = t % 36;
    const int dx = cell / 6 - 3, dy = cell % 6 - 3;
    const float* pmb = pm + (size_t)b * 50176;
    {
        int cx = clip_coord(gt[b * 16 + lm * 2 + 0]);
        int cy = clip_coord(gt[b * 16 + lm * 2 + 1]);
        out[8192 + b * 288 + t] = pmb[(cx + dx) * 224 + (cy + dy)];
    }
    {
        int cx = clip_coord(pred[b * 16 + lm * 2 + 0]);
        int cy = clip_coord(pred[b * 16 + lm * 2 + 1]);
        out[8192 + 147456 + b * 288 + t] = pmb[(cx + dx) * 224 + (cy + dy)];
    }
}

extern "C" void kernel_launch(void* const* d_in, const int* in_sizes, int n_in,
                              void* d_out, int out_size, void* d_ws, size_t ws_size,
                              hipStream_t stream)
{
    const float* pred_map = (const float*)d_in[0];
    const float* gt       = (const float*)d_in[1];
    const float* W1       = (const float*)d_in[2];
    const float* b1       = (const float*)d_in[3];
    const float* W2       = (const float*)d_in[4];
    const float* b2       = (const float*)d_in[5];
    const float* W3       = (const float*)d_in[6];
    const float* b3       = (const float*)d_in[7];
    float* out = (float*)d_out;

    float* h1   = (float*)d_ws;          // 262144 floats
    float* h2   = h1 + 262144;           // 131072 floats
    float* part = h2 + 131072;           // S * 262144 floats

    // pick largest split-K factor fitting the workspace (prev round proved >= 18 MB)
    static const int cand[] = {64, 56, 48, 40, 32, 24, 16, 8, 4, 2, 1};
    int S = 1;
    for (int i = 0; i < 11; ++i) {
        size_t need = (size_t)(393216 + (size_t)cand[i] * 262144) * sizeof(float);
        if (need <= ws_size) { S = cand[i]; break; }
    }
    const int steps_per = NSTEPS / S;
    const int rem       = NSTEPS % S;

    hipLaunchKernelGGL(gemm1_mfma, dim3(2, 2, S), dim3(512), 0, stream,
                       pred_map, W1, part, steps_per, rem);
    hipLaunchKernelGGL(reduce_bias_relu, dim3(262144 / 256), dim3(256), 0, stream,
                       part, b1, h1, S);
    hipLaunchKernelGGL(gemm2_k, dim3(131072 / 256), dim3(256), 0, stream, h1, W2, b2, h2);
    hipLaunchKernelGGL(gemm3_sig, dim3(8192 / 256), dim3(256), 0, stream, h2, W3, b3, out);
    hipLaunchKernelGGL(patches_k, dim3(512), dim3(288), 0, stream, pred_map, gt, out, out);
}

// Round 4
// 165.344 us; speedup vs baseline: 2.5580x; 1.5996x over previous
//
#include <hip/hip_runtime.h>
#include <math.h>

typedef __fp16   h16x2 __attribute__((ext_vector_type(2)));   // cvt_pkrtz result type
typedef _Float16 f16x8 __attribute__((ext_vector_type(8)));
typedef __attribute__((ext_vector_type(4))) float f32x4;

#define KDIM 50176
#define NDIM 512
#define MDIM 512
#define BM 256
#define BN 128
#define BK 32

// fp16 two-plane split: h = rtz_fp16(a), l = rn_fp16((a - float(h)) * 2048)
// residual computed from the STORED h value, so any cvt denorm-flush self-heals.
__device__ __forceinline__ void split_pair(float a, float b, unsigned& hw, unsigned& lw) {
    h16x2 hp = __builtin_amdgcn_cvt_pkrtz(a, b);
    float ra = (a - (float)hp[0]) * 2048.0f;
    float rb = (b - (float)hp[1]) * 2048.0f;
    h16x2 lp;
    lp[0] = (__fp16)ra;   // RN
    lp[1] = (__fp16)rb;
    union { h16x2 v; unsigned u; } cu;
    cu.v = hp; hw = cu.u;
    cu.v = lp; lw = cu.u;
}

// ---- GEMM1: part[z] = A[:, kz] @ W1[kz, :]  via fp16 2-plane MFMA (3 products) ----
// A plane scales: Ah x1, Al x2^11. W pre-scaled by 64: Wh = w*2^6, Wl = w*2^17.
// C = acc0 * 2^-6 + acc1 * 2^-17.
__global__ __launch_bounds__(512, 2) void gemm1_mfma(
    const float* __restrict__ A,      // [512][50176]
    const float* __restrict__ W,      // [50176][512]
    float* __restrict__ part,         // [S][512][512]
    int steps)
{
    __shared__ unsigned short Ahs[2][256][40];   // 40-half rows: 16B-aligned, 2-way-free b128 reads
    __shared__ unsigned short Als[2][256][40];
    __shared__ unsigned short Bhs[2][128][40];
    __shared__ unsigned short Bls[2][128][40];

    const int t = threadIdx.x;
    const int bm = blockIdx.x, bn = blockIdx.y, z = blockIdx.z;
    const int kbase = z * steps * BK;

    const int lane = t & 63, wave = t >> 6;
    const int wm = wave >> 1, wn = wave & 1;     // 4x2 wave grid, 64x64 per wave
    const int l15 = lane & 15, lh = lane >> 4;

    const bool isW = (t < 256);
    const int u = isW ? t : (t - 256);
    const int wkb = u & 7, wn0 = (u >> 3) * 4;   // W micro: 4k x 4n
    const int achunk = u & 7, arow0 = u >> 3;    // A: 8 rows (stride 32), one chunk

    f32x4 acc0[4][4], acc1[4][4];
#pragma unroll
    for (int i = 0; i < 4; ++i)
#pragma unroll
        for (int j = 0; j < 4; ++j) { acc0[i][j] = (f32x4)0.f; acc1[i][j] = (f32x4)0.f; }

    float4 reg[8];
    auto gload = [&](int s) {
        const int k0 = kbase + s * BK;
        if (isW) {
            const float* Wb = W + (size_t)k0 * NDIM + bn * BN + wn0;
#pragma unroll
            for (int i = 0; i < 4; ++i)
                reg[i] = *(const float4*)(Wb + (size_t)(wkb * 4 + i) * NDIM);
        } else {
            const float* Ab = A + (size_t)(bm * BM) * KDIM + k0 + achunk * 4;
#pragma unroll
            for (int j = 0; j < 8; ++j)
                reg[j] = *(const float4*)(Ab + (size_t)(arow0 + 32 * j) * KDIM);
        }
    };

    auto stage = [&](int buf) {
        if (isW) {
#pragma unroll
            for (int j = 0; j < 4; ++j) {
                unsigned h01, l01, h23, l23;
                float v0 = ((const float*)&reg[0])[j] * 64.0f;
                float v1 = ((const float*)&reg[1])[j] * 64.0f;
                float v2 = ((const float*)&reg[2])[j] * 64.0f;
                float v3 = ((const float*)&reg[3])[j] * 64.0f;
                split_pair(v0, v1, h01, l01);
                split_pair(v2, v3, h23, l23);
                *(uint2*)&Bhs[buf][wn0 + j][wkb * 4] = make_uint2(h01, h23);
                *(uint2*)&Bls[buf][wn0 + j][wkb * 4] = make_uint2(l01, l23);
            }
        } else {
#pragma unroll
            for (int j = 0; j < 8; ++j) {
                unsigned h01, l01, h23, l23;
                split_pair(reg[j].x, reg[j].y, h01, l01);
                split_pair(reg[j].z, reg[j].w, h23, l23);
                *(uint2*)&Ahs[buf][arow0 + 32 * j][achunk * 4] = make_uint2(h01, h23);
                *(uint2*)&Als[buf][arow0 + 32 * j][achunk * 4] = make_uint2(l01, l23);
            }
        }
    };

    auto compute = [&](int buf) {
        f16x8 bhf[4], blf[4];
#pragma unroll
        for (int nf = 0; nf < 4; ++nf) {
            bhf[nf] = *(const f16x8*)&Bhs[buf][wn * 64 + nf * 16 + l15][lh * 8];
            blf[nf] = *(const f16x8*)&Bls[buf][wn * 64 + nf * 16 + l15][lh * 8];
        }
#pragma unroll
        for (int mf = 0; mf < 4; ++mf) {
            f16x8 ah = *(const f16x8*)&Ahs[buf][wm * 64 + mf * 16 + l15][lh * 8];
            f16x8 al = *(const f16x8*)&Als[buf][wm * 64 + mf * 16 + l15][lh * 8];
#pragma unroll
            for (int nf = 0; nf < 4; ++nf) {
                acc0[mf][nf] = __builtin_amdgcn_mfma_f32_16x16x32_f16(ah, bhf[nf], acc0[mf][nf], 0, 0, 0);
                acc1[mf][nf] = __builtin_amdgcn_mfma_f32_16x16x32_f16(ah, blf[nf], acc1[mf][nf], 0, 0, 0);
                acc1[mf][nf] = __builtin_amdgcn_mfma_f32_16x16x32_f16(al, bhf[nf], acc1[mf][nf], 0, 0, 0);
            }
        }
    };

    gload(0);
    stage(0);
    __syncthreads();
    int cur = 0;
    for (int s = 0; s < steps; ++s) {
        if (s + 1 < steps) gload(s + 1);       // issue next-tile loads (latency hides under MFMA)
        compute(cur);
        if (s + 1 < steps) stage(cur ^ 1);     // vmcnt wait auto-inserted at first reg use
        __syncthreads();
        cur ^= 1;
    }

    const float c0 = 1.0f / 64.0f;
    const float c1 = 1.0f / 131072.0f;
    float* Cp = part + (size_t)z * (MDIM * NDIM);
    const int row0 = bm * BM + wm * 64;
    const int col0 = bn * BN + wn * 64;
#pragma unroll
    for (int mf = 0; mf < 4; ++mf)
#pragma unroll
        for (int nf = 0; nf < 4; ++nf) {
            const int r0 = row0 + mf * 16 + lh * 4;
            const int c = col0 + nf * 16 + l15;
#pragma unroll
            for (int r = 0; r < 4; ++r)
                Cp[(size_t)(r0 + r) * NDIM + c] = acc0[mf][nf][r] * c0 + acc1[mf][nf][r] * c1;
        }
}

// ---------------- reduce partials + bias + relu -> h1 (float4) ----------------
__global__ __launch_bounds__(256) void reduce_bias_relu(
    const float4* __restrict__ part, const float* __restrict__ b1,
    float4* __restrict__ h1, int S)
{
    int i = blockIdx.x * 256 + threadIdx.x;      // 0..65535 float4s
    float4 s = make_float4(0.f, 0.f, 0.f, 0.f);
    for (int z = 0; z < S; ++z) {
        float4 v = part[(size_t)z * 65536 + i];
        s.x += v.x; s.y += v.y; s.z += v.z; s.w += v.w;
    }
    int nb = (i & 127) * 4;
    s.x = fmaxf(s.x + b1[nb + 0], 0.f);
    s.y = fmaxf(s.y + b1[nb + 1], 0.f);
    s.z = fmaxf(s.z + b1[nb + 2], 0.f);
    s.w = fmaxf(s.w + b1[nb + 3], 0.f);
    h1[i] = s;
}

// ---------------- layer 2: h2 = relu(h1 @ W2 + b2) ----------------
__global__ __launch_bounds__(256) void gemm2_k(
    const float* __restrict__ h1, const float* __restrict__ W2,
    const float* __restrict__ b2, float* __restrict__ h2)
{
    int g = blockIdx.x * 256 + threadIdx.x;     // 0..131071
    int m = g >> 8, n = g & 255;
    const float* a = h1 + (size_t)m * 512;
    float sum = 0.f;
#pragma unroll 8
    for (int k = 0; k < 512; ++k) sum = fmaf(a[k], W2[(size_t)k * 256 + n], sum);
    sum += b2[n];
    h2[g] = fmaxf(sum, 0.f);
}

// ---------------- layer 3: pred = sigmoid(h2 @ W3 + b3) ----------------
__global__ __launch_bounds__(256) void gemm3_sig(
    const float* __restrict__ h2, const float* __restrict__ W3,
    const float* __restrict__ b3, float* __restrict__ pred)
{
    int g = blockIdx.x * 256 + threadIdx.x;     // 0..8191
    int m = g >> 4, j = g & 15;
    const float* a = h2 + (size_t)m * 256;
    float sum = 0.f;
#pragma unroll 8
    for (int k = 0; k < 256; ++k) sum = fmaf(a[k], W3[(size_t)k * 16 + j], sum);
    sum += b3[j];
    pred[g] = 1.f / (1.f + expf(-sum));
}

// ---------------- patch gathers ----------------
__device__ __forceinline__ int clip_coord(float v) {
    int c = (int)(v * 224.0f);
    if (c >= 219) c = 200;
    if (c <= 5)   c = 8;
    return c;
}

__global__ void patches_k(
    const float* __restrict__ pm, const float* __restrict__ gt,
    const float* __restrict__ pred, float* __restrict__ out)
{
    const int b = blockIdx.x;
    const int t = threadIdx.x;          // 0..287
    const int lm = t / 36, cell = t % 36;
    const int dx = cell / 6 - 3, dy = cell % 6 - 3;
    const float* pmb = pm + (size_t)b * 50176;
    {
        int cx = clip_coord(gt[b * 16 + lm * 2 + 0]);
        int cy = clip_coord(gt[b * 16 + lm * 2 + 1]);
        out[8192 + b * 288 + t] = pmb[(cx + dx) * 224 + (cy + dy)];
    }
    {
        int cx = clip_coord(pred[b * 16 + lm * 2 + 0]);
        int cy = clip_coord(pred[b * 16 + lm * 2 + 1]);
        out[8192 + 147456 + b * 288 + t] = pmb[(cx + dx) * 224 + (cy + dy)];
    }
}

extern "C" void kernel_launch(void* const* d_in, const int* in_sizes, int n_in,
                              void* d_out, int out_size, void* d_ws, size_t ws_size,
                              hipStream_t stream)
{
    const float* pred_map = (const float*)d_in[0];
    const float* gt       = (const float*)d_in[1];
    const float* W1       = (const float*)d_in[2];
    const float* b1       = (const float*)d_in[3];
    const float* W2       = (const float*)d_in[4];
    const float* b2       = (const float*)d_in[5];
    const float* W3       = (const float*)d_in[6];
    const float* b3       = (const float*)d_in[7];
    float* out = (float*)d_out;

    float* h1   = (float*)d_ws;          // 262144 floats
    float* h2   = h1 + 262144;           // 131072 floats
    float* part = h2 + 131072;           // S * 262144 floats

    // largest split-K factor (dividing 1568) that fits the workspace
    static const int cand[] = {32, 16, 8, 4, 2, 1};
    int S = 1;
    for (int i = 0; i < 6; ++i) {
        size_t need = (size_t)(393216 + (size_t)cand[i] * 262144) * sizeof(float);
        if (need <= ws_size) { S = cand[i]; break; }
    }
    const int steps = 1568 / S;

    hipLaunchKernelGGL(gemm1_mfma, dim3(2, 4, S), dim3(512), 0, stream,
                       pred_map, W1, part, steps);
    hipLaunchKernelGGL(reduce_bias_relu, dim3(256), dim3(256), 0, stream,
                       (const float4*)part, b1, (float4*)h1, S);
    hipLaunchKernelGGL(gemm2_k, dim3(131072 / 256), dim3(256), 0, stream, h1, W2, b2, h2);
    hipLaunchKernelGGL(gemm3_sig, dim3(8192 / 256), dim3(256), 0, stream, h2, W3, b3, out);
    hipLaunchKernelGGL(patches_k, dim3(512), dim3(288), 0, stream, pred_map, gt, out, out);
}